// Round 1
// baseline (290.018 us; speedup 1.0000x reference)
//
#include <hip/hip_runtime.h>

// Depthwise 5x5 box blur, zero 'same' padding.
// x: (16, 8, 512, 512) fp32 -> out: same shape.
//
// LDS-free streaming formulation. Each thread owns 2 output columns and
// streams down a 32-row band with a vertical sliding sum held in registers
// for its 2 columns + 2-column halos on each side (6 running sums).
// Horizontal 5-sum is then pure register arithmetic. Halo-column loads and
// outgoing-row subtract loads hit L1/L2 (same cache lines), so HBM traffic
// stays at ~1x read + 1x write. No LDS, no barriers -> 8 blocks/CU,
// 32 waves/CU, loads continuously in flight.

#define H 512
#define W 512
#define RB 32              // output rows per block
#define NB (H / RB)        // 16 row bands

__device__ __forceinline__ float2 ld2(const float* p) {
    return *reinterpret_cast<const float2*>(p);
}

__global__ __launch_bounds__(256, 8) void avefilter_kernel(
    const float* __restrict__ x, const float* __restrict__ wgt,
    float* __restrict__ out)
{
    const int t     = threadIdx.x;      // 0..255, owns cols 2t, 2t+1
    const int band  = blockIdx.x;       // 0..15
    const int plane = blockIdx.y;       // n*C + c, 0..127
    const int c0    = t * 2;
    const int r0    = band * RB;

    const float* in = x + (size_t)plane * (H * W);
    const float scale = wgt[0];         // == 1/25 (uniform kernel)

    const bool hL = (t != 0);           // left halo exists (cols c0-2, c0-1)
    const bool hR = (t != 255);         // right halo exists (cols c0+2, c0+3)
    const float2 z = make_float2(0.f, 0.f);

    // Vertical sliding sums over the 5-row window for 6 columns:
    // sl = cols c0-2, c0-1 | sm = cols c0, c0+1 | sr = cols c0+2, c0+3
    float2 sl = z, sm = z, sr = z;

    // Prime the window with rows r0-2 .. r0+1 (clipped at the top edge).
    for (int rr = r0 - 2; rr <= r0 + 1; ++rr) {
        if (rr >= 0) {                  // rr <= 481 < H always
            const float* p = in + (size_t)rr * W + c0;
            float2 a = hL ? ld2(p - 2) : z;
            float2 b = ld2(p);
            float2 c = hR ? ld2(p + 2) : z;
            sl.x += a.x; sl.y += a.y;
            sm.x += b.x; sm.y += b.y;
            sr.x += c.x; sr.y += c.y;
        }
    }

    const float* pn = in + (size_t)(r0 + 2) * W + c0;  // incoming row r+2
    const float* po = in + (size_t)(r0 - 2) * W + c0;  // outgoing row r-2
    float* op = out + (size_t)plane * (H * W) + (size_t)r0 * W + c0;

    #pragma unroll 4
    for (int i = 0; i < RB; ++i) {
        const int r = r0 + i;

        // Slide in row r+2 (uniform branch; false only for last band's tail).
        if (r + 2 < H) {
            float2 a = hL ? ld2(pn - 2) : z;
            float2 b = ld2(pn);
            float2 c = hR ? ld2(pn + 2) : z;
            sl.x += a.x; sl.y += a.y;
            sm.x += b.x; sm.y += b.y;
            sr.x += c.x; sr.y += c.y;
        }

        // Horizontal 5-sum from the 6 vertical sums (shared subexpression).
        float a1 = sl.y + sm.x + sm.y;        // cols c0-1 + c0 + c0+1
        float h0 = (sl.x + a1) + sr.x;        // window c0-2 .. c0+2
        float h1 = (a1 + sr.x) + sr.y;        // window c0-1 .. c0+3
        *reinterpret_cast<float2*>(op) = make_float2(h0 * scale, h1 * scale);

        // Slide out row r-2 (re-load; L1/L2 hit — loaded 4 iters ago).
        if (r - 2 >= 0) {
            float2 a = hL ? ld2(po - 2) : z;
            float2 b = ld2(po);
            float2 c = hR ? ld2(po + 2) : z;
            sl.x -= a.x; sl.y -= a.y;
            sm.x -= b.x; sm.y -= b.y;
            sr.x -= c.x; sr.y -= c.y;
        }

        pn += W; po += W; op += W;
    }
}

extern "C" void kernel_launch(void* const* d_in, const int* in_sizes, int n_in,
                              void* d_out, int out_size, void* d_ws, size_t ws_size,
                              hipStream_t stream) {
    const float* x   = (const float*)d_in[0];
    const float* wgt = (const float*)d_in[1];
    float* out = (float*)d_out;

    dim3 grid(NB, 16 * 8);   // 16 bands x 128 planes = 2048 blocks (8/CU)
    dim3 block(256);
    avefilter_kernel<<<grid, block, 0, stream>>>(x, wgt, out);
}

// Round 4
// 234.959 us; speedup vs baseline: 1.2343x; 1.2343x over previous
//
#include <hip/hip_runtime.h>

// Depthwise 5x5 box blur, zero 'same' padding.
// x: (16, 8, 512, 512) fp32 -> out: same shape.
//
// v0 structure (LDS tile + register sliding vertical sums) with the LDS
// halved via column-split tiles to raise occupancy 3 -> 7 blocks/CU.
// Tile: 16 rows x 256 cols output; stages 20 rows x 264 cols = 21.1 KB LDS.
// (Resubmission: rounds 2-3 hit container-infra failures, no kernel verdict.
//  Defensive change: no min-waves launch_bounds hint; LDS alone gives 7/CU.)

#define H 512
#define W 512
#define TH 16               // output rows per block
#define TW 256              // output cols per block
#define LROWS (TH + 4)      // 20 staged rows (2-halo each side)
#define LCOLS (TW + 8)      // 264 floats: data col gc lives at l = gc-(gc0-4)
#define NV (LCOLS / 4)      // 66 float4 per staged row (1056 B, 16B-aligned)

__global__ __launch_bounds__(256) void avefilter_kernel(
    const float* __restrict__ x, const float* __restrict__ wgt,
    float* __restrict__ out)
{
    __shared__ float smem[LROWS * LCOLS];   // 21120 B -> 7 blocks/CU

    const int tid   = threadIdx.x;
    const int bx    = blockIdx.x;           // 0..63: (row tile)*2 + col tile
    const int rt    = bx >> 1;
    const int ct    = bx & 1;
    const int plane = blockIdx.y;           // n*C + c, 0..127

    const int r0  = rt * TH;                // first output row
    const int gc0 = ct * TW;                // first output col

    const float* in   = x   + (size_t)plane * (H * W);
    float*       outp = out + (size_t)plane * (H * W);
    const float scale = wgt[0];             // == 1/25 (uniform kernel)

    // Stage 20 rows x 66 float4 (cols gc0-4 .. gc0+259). Edge float4s are
    // entirely in or out of range (gc0, W multiples of 4), so whole-vector
    // zeroing handles both row and column padding. 1320 float4 ops, fully
    // coalesced, ~5.2 per thread.
    for (int i = tid; i < LROWS * NV; i += 256) {
        const int lr = i / NV;
        const int lv = i - lr * NV;
        const int gr = r0 - 2 + lr;
        const int gc = gc0 - 4 + lv * 4;
        float4 v = make_float4(0.f, 0.f, 0.f, 0.f);
        if (gr >= 0 && gr < H && gc >= 0 && gc < W) {
            v = *(const float4*)(in + (size_t)gr * W + gc);
        }
        *(float4*)(smem + lr * LCOLS + lv * 4) = v;
    }
    __syncthreads();

    // Each thread: one output column gc0+tid, 16 rows. Horizontal 5-sums
    // from LDS (consecutive lanes -> consecutive addrs, <=2-way aliasing =
    // free), vertical 5-window slides in registers via h[5] rotation.
    const float* bcol = smem + tid + 2;     // window cols tid+2 .. tid+6

    float h[5];
    #pragma unroll
    for (int i = 0; i < 5; ++i) {
        const float* b = bcol + i * LCOLS;
        h[i] = b[0] + b[1] + b[2] + b[3] + b[4];
    }

    #pragma unroll
    for (int r = 0; r < TH; ++r) {
        float s = h[0] + h[1] + h[2] + h[3] + h[4];
        outp[(size_t)(r0 + r) * W + gc0 + tid] = s * scale;
        if (r < TH - 1) {
            const float* b = bcol + (r + 5) * LCOLS;
            h[r % 5] = b[0] + b[1] + b[2] + b[3] + b[4];
        }
    }
}

extern "C" void kernel_launch(void* const* d_in, const int* in_sizes, int n_in,
                              void* d_out, int out_size, void* d_ws, size_t ws_size,
                              hipStream_t stream) {
    const float* x   = (const float*)d_in[0];
    const float* wgt = (const float*)d_in[1];
    float* out = (float*)d_out;

    dim3 grid((H / TH) * 2, 16 * 8);   // 64 tiles x 128 planes = 8192 blocks
    dim3 block(256);
    avefilter_kernel<<<grid, block, 0, stream>>>(x, wgt, out);
}

// Round 5
// 231.739 us; speedup vs baseline: 1.2515x; 1.0139x over previous
//
#include <hip/hip_runtime.h>

// Depthwise 5x5 box blur, zero 'same' padding.
// x: (16, 8, 512, 512) fp32 -> out: same shape.
//
// LDS-free streaming v2 (round-1 failure modes fixed):
//  - hsum 5-slot register ring: every input row loaded ONCE (no subtract
//    re-loads; round-1 had 2 dependent load batches/iter).
//  - all loads UNCONDITIONAL: row index clamped to [0,H-1], out-of-range
//    rows/cols zeroed by multiplicative masks (wave-uniform for rows).
//    Round-1's `if (r+2<H)` guards blocked cross-iteration load hoisting.
//  - explicit 1-deep prefetch: row r+3's 3 loads issued before consuming
//    row r+2; full unroll so cur/next are SSA-renamed (no copies).
// Each thread: 4 cols x 16 rows, float4 stores. No LDS, no barriers.
// 2048 blocks x 4 waves = 8192 waves = one full-resident generation.

#define H 512
#define W 512
#define RB 32              // band rows per block
#define GR 16              // rows per thread (2 groups of 128 threads)

struct RowV { float2 l; float4 m; float2 r; };   // cols c0-2..c0+5

__device__ __forceinline__ RowV load_row(const float* __restrict__ in, int rr,
                                         int offL, int c0, int offR) {
    const int rc = rr < 0 ? 0 : (rr > (H - 1) ? (H - 1) : rr);  // clamp: addr always valid
    const float* p = in + (size_t)rc * W;
    RowV v;
    v.l = *reinterpret_cast<const float2*>(p + offL);
    v.m = *reinterpret_cast<const float4*>(p + c0);
    v.r = *reinterpret_cast<const float2*>(p + offR);
    return v;
}

// 4 horizontal 5-sums for cols c0..c0+3 from the 8-value window, with
// edge masks mL/mR (per-thread) and row mask mrow (wave-uniform).
__device__ __forceinline__ void hsum4(const RowV& v, float mrow, float mL, float mR,
                                      float& s0, float& s1, float& s2, float& s3) {
    const float a0 = v.l.x * mL, a1 = v.l.y * mL;   // cols c0-2, c0-1
    const float b4 = v.r.x * mR, b5 = v.r.y * mR;   // cols c0+4, c0+5
    const float t1 = v.m.x + v.m.y;                 // v0+v1
    const float t2 = v.m.z + v.m.w;                 // v2+v3
    s0 = (a0 + a1 + t1 + v.m.z) * mrow;             // c0-2 .. c0+2
    s1 = (a1 + t1 + t2) * mrow;                     // c0-1 .. c0+3
    s2 = (t1 + t2 + b4) * mrow;                     // c0   .. c0+4
    s3 = (v.m.y + t2 + b4 + b5) * mrow;             // c0+1 .. c0+5
}

__global__ __launch_bounds__(256) void avefilter_kernel(
    const float* __restrict__ x, const float* __restrict__ wgt,
    float* __restrict__ out)
{
    const int t     = threadIdx.x;
    const int g     = t >> 7;             // row-half of the band (0/1)
    const int lt    = t & 127;            // column-lane: owns cols 4*lt..4*lt+3
    const int c0    = lt << 2;
    const int plane = blockIdx.y;         // n*C + c, 0..127
    const int r0    = blockIdx.x * RB + g * GR;   // first output row

    const float* in = x + (size_t)plane * (H * W);
    float* op = out + (size_t)plane * (H * W) + (size_t)r0 * W + c0;
    const float scale = wgt[0];           // == 1/25 (uniform kernel)

    const float mL = (lt != 0)   ? 1.f : 0.f;
    const float mR = (lt != 127) ? 1.f : 0.f;
    const int  offL = (lt != 0)   ? (c0 - 2) : c0;   // clamped: addr valid, value masked
    const int  offR = (lt != 127) ? (c0 + 4) : c0;

    // 5-slot hsum ring per column. Row r0+2+i lands in slot (i+4)%5, which is
    // exactly the slot of the row leaving the 5-row window. Vertical sum is
    // order-independent, so slot identity doesn't matter. All indices static.
    float h[4][5];

    // ---- prime: rows r0-2..r0+1 -> slots 0..3; row r0+2 -> cur (in flight)
    RowV p0  = load_row(in, r0 - 2, offL, c0, offR);
    RowV p1  = load_row(in, r0 - 1, offL, c0, offR);
    RowV p2  = load_row(in, r0,     offL, c0, offR);
    RowV p3  = load_row(in, r0 + 1, offL, c0, offR);
    RowV cur = load_row(in, r0 + 2, offL, c0, offR);

    const float mtop = (r0 == 0) ? 0.f : 1.f;        // rows -2,-1 only at band 0, g 0
    hsum4(p0, mtop, mL, mR, h[0][0], h[1][0], h[2][0], h[3][0]);
    hsum4(p1, mtop, mL, mR, h[0][1], h[1][1], h[2][1], h[3][1]);
    hsum4(p2, 1.f,  mL, mR, h[0][2], h[1][2], h[2][2], h[3][2]);
    hsum4(p3, 1.f,  mL, mR, h[0][3], h[1][3], h[2][3], h[3][3]);

    // ---- steady: emit rows r0..r0+14 with 1-deep prefetch
    #pragma unroll
    for (int i = 0; i < GR - 1; ++i) {
        RowV nxt = load_row(in, r0 + 3 + i, offL, c0, offR);  // prefetch r+3
        const int   s    = (i + 4) % 5;                       // static per unrolled i
        const float mrow = ((unsigned)(r0 + 2 + i) < (unsigned)H) ? 1.f : 0.f;
        hsum4(cur, mrow, mL, mR, h[0][s], h[1][s], h[2][s], h[3][s]);
        float4 o;
        o.x = (h[0][0] + h[0][1] + h[0][2] + h[0][3] + h[0][4]) * scale;
        o.y = (h[1][0] + h[1][1] + h[1][2] + h[1][3] + h[1][4]) * scale;
        o.z = (h[2][0] + h[2][1] + h[2][2] + h[2][3] + h[2][4]) * scale;
        o.w = (h[3][0] + h[3][1] + h[3][2] + h[3][3] + h[3][4]) * scale;
        *reinterpret_cast<float4*>(op + (size_t)i * W) = o;
        cur = nxt;
    }
    // ---- peeled last row (no prefetch)
    {
        const int   i    = GR - 1;
        const int   s    = (i + 4) % 5;
        const float mrow = ((unsigned)(r0 + 2 + i) < (unsigned)H) ? 1.f : 0.f;
        hsum4(cur, mrow, mL, mR, h[0][s], h[1][s], h[2][s], h[3][s]);
        float4 o;
        o.x = (h[0][0] + h[0][1] + h[0][2] + h[0][3] + h[0][4]) * scale;
        o.y = (h[1][0] + h[1][1] + h[1][2] + h[1][3] + h[1][4]) * scale;
        o.z = (h[2][0] + h[2][1] + h[2][2] + h[2][3] + h[2][4]) * scale;
        o.w = (h[3][0] + h[3][1] + h[3][2] + h[3][3] + h[3][4]) * scale;
        *reinterpret_cast<float4*>(op + (size_t)i * W) = o;
    }
}

extern "C" void kernel_launch(void* const* d_in, const int* in_sizes, int n_in,
                              void* d_out, int out_size, void* d_ws, size_t ws_size,
                              hipStream_t stream) {
    const float* x   = (const float*)d_in[0];
    const float* wgt = (const float*)d_in[1];
    float* out = (float*)d_out;

    dim3 grid(H / RB, 16 * 8);   // 16 bands x 128 planes = 2048 blocks
    dim3 block(256);
    avefilter_kernel<<<grid, block, 0, stream>>>(x, wgt, out);
}

// Round 6
// 230.384 us; speedup vs baseline: 1.2588x; 1.0059x over previous
//
#include <hip/hip_runtime.h>

// Depthwise 5x5 box blur, zero 'same' padding.
// x: (16, 8, 512, 512) fp32 -> out: same shape.
//
// Streaming v3: batch-of-4 double-buffered row loads to force deep MLP.
// Round-5 post-mortem: VGPR=36 proved the compiler kept only ONE 32B row
// batch in flight per wave (~4KB/CU outstanding -> 2.7 TB/s). Two named
// 4-row register buffers (64 VGPRs of load destinations) + issue batch
// b+2 after consuming batch b keeps 4-8 rows (128-256B/thread) in flight
// continuously. __launch_bounds__(256,4) permits up to 128 VGPRs.
// Math identical to verified v2: clamped addresses + multiplicative edge
// masks, 5-slot hsum ring, every input row loaded exactly once.

#define H 512
#define W 512
#define RB 32              // band rows per block (2 groups of 128 threads)
#define NBATCH 5           // 20 consumed rows per thread = 5 batches of 4

struct RowV { float2 l; float4 m; float2 r; };   // cols c0-2..c0+5

__device__ __forceinline__ RowV load_row(const float* __restrict__ in, int rr,
                                         int offL, int c0, int offR) {
    const int rc = rr < 0 ? 0 : (rr > (H - 1) ? (H - 1) : rr);  // addr always valid
    const float* p = in + (size_t)rc * W;
    RowV v;
    v.l = *reinterpret_cast<const float2*>(p + offL);
    v.m = *reinterpret_cast<const float4*>(p + c0);
    v.r = *reinterpret_cast<const float2*>(p + offR);
    return v;
}

// 4 horizontal 5-sums for cols c0..c0+3; mL/mR per-thread edge masks,
// mrow wave-uniform row mask (zero-padding realized multiplicatively).
__device__ __forceinline__ void hsum4(const RowV& v, float mrow, float mL, float mR,
                                      float& s0, float& s1, float& s2, float& s3) {
    const float a0 = v.l.x * mL, a1 = v.l.y * mL;   // cols c0-2, c0-1
    const float b4 = v.r.x * mR, b5 = v.r.y * mR;   // cols c0+4, c0+5
    const float t1 = v.m.x + v.m.y;
    const float t2 = v.m.z + v.m.w;
    s0 = (a0 + a1 + t1 + v.m.z) * mrow;             // c0-2 .. c0+2
    s1 = (a1 + t1 + t2) * mrow;                     // c0-1 .. c0+3
    s2 = (t1 + t2 + b4) * mrow;                     // c0   .. c0+4
    s3 = (v.m.y + t2 + b4 + b5) * mrow;             // c0+1 .. c0+5
}

__global__ __launch_bounds__(256, 4) void avefilter_kernel(
    const float* __restrict__ x, const float* __restrict__ wgt,
    float* __restrict__ out)
{
    const int t     = threadIdx.x;
    const int g     = t >> 7;             // row-half of the band (0/1)
    const int lt    = t & 127;            // owns cols 4*lt .. 4*lt+3
    const int c0    = lt << 2;
    const int plane = blockIdx.y;         // n*C + c, 0..127
    const int r0    = blockIdx.x * RB + g * 16;    // first output row (16/thread)

    const float* in = x + (size_t)plane * (H * W);
    float* op = out + (size_t)plane * (H * W) + (size_t)r0 * W + c0;
    const float scale = wgt[0];           // == 1/25 (uniform kernel)

    const float mL = (lt != 0)   ? 1.f : 0.f;
    const float mR = (lt != 127) ? 1.f : 0.f;
    const int  offL = (lt != 0)   ? (c0 - 2) : c0;
    const int  offR = (lt != 127) ? (c0 + 4) : c0;

    // Consumed rows: rr = r0-2+i, i = 0..19. hsum ring slot = i%5; output
    // row r0+(i-4) emitted once i>=4 (window i-4..i = all 5 slots).
    RowV bufA[4], bufB[4];                // 2 x 4-row load buffers (64 VGPRs)
    float h[4][5];

    #pragma unroll
    for (int j = 0; j < 4; ++j) bufA[j] = load_row(in, r0 - 2 + j, offL, c0, offR);
    #pragma unroll
    for (int j = 0; j < 4; ++j) bufB[j] = load_row(in, r0 + 2 + j, offL, c0, offR);

#define DO_BATCH(BUF, B)                                                      \
    {                                                                         \
        _Pragma("unroll")                                                     \
        for (int j = 0; j < 4; ++j) {                                         \
            const int i  = (B) * 4 + j;                                       \
            const int rr = r0 - 2 + i;                                        \
            const float mrow = ((unsigned)rr < (unsigned)H) ? 1.f : 0.f;      \
            const int s = i % 5;                                              \
            hsum4(BUF[j], mrow, mL, mR, h[0][s], h[1][s], h[2][s], h[3][s]);  \
            if (i >= 4) {                                                     \
                float4 o;                                                     \
                o.x = (h[0][0]+h[0][1]+h[0][2]+h[0][3]+h[0][4]) * scale;      \
                o.y = (h[1][0]+h[1][1]+h[1][2]+h[1][3]+h[1][4]) * scale;      \
                o.z = (h[2][0]+h[2][1]+h[2][2]+h[2][3]+h[2][4]) * scale;      \
                o.w = (h[3][0]+h[3][1]+h[3][2]+h[3][3]+h[3][4]) * scale;      \
                *reinterpret_cast<float4*>(op + (size_t)(i - 4) * W) = o;     \
            }                                                                 \
        }                                                                     \
        if ((B) + 2 < NBATCH) {                                               \
            _Pragma("unroll")                                                 \
            for (int j = 0; j < 4; ++j)                                       \
                BUF[j] = load_row(in, r0 - 2 + ((B) + 2) * 4 + j,             \
                                  offL, c0, offR);                            \
        }                                                                     \
    }

    DO_BATCH(bufA, 0)
    DO_BATCH(bufB, 1)
    DO_BATCH(bufA, 2)
    DO_BATCH(bufB, 3)
    DO_BATCH(bufA, 4)
#undef DO_BATCH
}

extern "C" void kernel_launch(void* const* d_in, const int* in_sizes, int n_in,
                              void* d_out, int out_size, void* d_ws, size_t ws_size,
                              hipStream_t stream) {
    const float* x   = (const float*)d_in[0];
    const float* wgt = (const float*)d_in[1];
    float* out = (float*)d_out;

    dim3 grid(H / RB, 16 * 8);   // 16 bands x 128 planes = 2048 blocks
    dim3 block(256);
    avefilter_kernel<<<grid, block, 0, stream>>>(x, wgt, out);
}

// Round 7
// 227.560 us; speedup vs baseline: 1.2745x; 1.0124x over previous
//
#include <hip/hip_runtime.h>

// Depthwise 5x5 box blur, zero 'same' padding.
// x: (16, 8, 512, 512) fp32 -> out: same shape.
//
// Streaming v4: inline-asm loads + hand-counted s_waitcnt vmcnt(N).
// Rounds 5-6 proved the compiler collapses any source-level double-buffer
// (VGPR=36 both times: one row-batch in flight, vmcnt(0) per row,
// ~4KB/CU outstanding -> 2.6 TB/s plateau). Here every row's 3 loads are
// asm volatile global_load_dwordx2/x4 into a 5-row register ring the
// allocator must keep live; consumption waits vmcnt(12) (= 4 rows always
// in flight, never drained to 0 until the tail). sched_barrier(0) after
// each wait stops VALU consumers hoisting past the asm waitcnt (rule:
// "memory" clobber does NOT order register-only ops).
// Math identical to the bench-verified v2/v3: clamped row addresses +
// multiplicative edge masks, 5-slot hsum ring, each row loaded once.

#define H 512
#define W 512
#define RB 32              // band rows per block (2 groups of 128 threads)

typedef float f32x4 __attribute__((ext_vector_type(4)));
typedef float f32x2 __attribute__((ext_vector_type(2)));

struct RowB { f32x2 l; f32x4 m; f32x2 r; };   // cols c0-2..c0+5

// Issue one row's 3 loads (l,m,r in FIFO order). Address clamped to a
// valid row; out-of-range values are zeroed by masks at consume time.
__device__ __forceinline__ void issue_row(RowB& b, const float* __restrict__ in,
                                          int rr, int offL, int c0, int offR) {
    const int rc = rr < 0 ? 0 : (rr > (H - 1) ? (H - 1) : rr);
    const float* p = in + (size_t)rc * W;
    asm volatile("global_load_dwordx2 %0, %1, off" : "=&v"(b.l) : "v"(p + offL));
    asm volatile("global_load_dwordx4 %0, %1, off" : "=&v"(b.m) : "v"(p + c0));
    asm volatile("global_load_dwordx2 %0, %1, off" : "=&v"(b.r) : "v"(p + offR));
}

// Wait until at most N vector-memory ops outstanding, then fence the
// scheduler so consumers cannot hoist above the wait.
#define WAITVM(N) do {                                            \
    asm volatile("s_waitcnt vmcnt(" #N ")" ::: "memory");         \
    __builtin_amdgcn_sched_barrier(0);                            \
} while (0)

// 4 horizontal 5-sums for cols c0..c0+3; mL/mR per-thread edge masks,
// mrow wave-uniform row mask (zero padding realized multiplicatively).
__device__ __forceinline__ void hsum4(const RowB& v, float mrow, float mL, float mR,
                                      float& s0, float& s1, float& s2, float& s3) {
    const float a0 = v.l.x * mL, a1 = v.l.y * mL;   // cols c0-2, c0-1
    const float b4 = v.r.x * mR, b5 = v.r.y * mR;   // cols c0+4, c0+5
    const float t1 = v.m.x + v.m.y;
    const float t2 = v.m.z + v.m.w;
    s0 = (a0 + a1 + t1 + v.m.z) * mrow;             // c0-2 .. c0+2
    s1 = (a1 + t1 + t2) * mrow;                     // c0-1 .. c0+3
    s2 = (t1 + t2 + b4) * mrow;                     // c0   .. c0+4
    s3 = (v.m.y + t2 + b4 + b5) * mrow;             // c0+1 .. c0+5
}

__global__ __launch_bounds__(256) void avefilter_kernel(
    const float* __restrict__ x, const float* __restrict__ wgt,
    float* __restrict__ out)
{
    const int t     = threadIdx.x;
    const int g     = t >> 7;             // row-half of the band (0/1)
    const int lt    = t & 127;            // owns cols 4*lt .. 4*lt+3
    const int c0    = lt << 2;
    const int plane = blockIdx.y;         // n*C + c, 0..127
    const int r0    = blockIdx.x * RB + g * 16;   // first output row (16/thread)

    const float* in = x + (size_t)plane * (H * W);
    float* op = out + (size_t)plane * (H * W) + (size_t)r0 * W + c0;
    const float scale = wgt[0];           // == 1/25 (uniform kernel)

    const float mL = (lt != 0)   ? 1.f : 0.f;
    const float mR = (lt != 127) ? 1.f : 0.f;
    const int  offL = (lt != 0)   ? (c0 - 2) : c0;
    const int  offR = (lt != 127) ? (c0 + 4) : c0;

    // Consumed rows: rr = r0-2+i, i = 0..19. Ring slot s = i%5 holds both
    // the in-flight load buffer and the hsum; output row r0+(i-4) once i>=4.
    RowB buf[5];
    float h[4][5];

    // Prologue: 4 rows (12 loads) in flight before any consumption.
    issue_row(buf[0], in, r0 - 2, offL, c0, offR);
    issue_row(buf[1], in, r0 - 1, offL, c0, offR);
    issue_row(buf[2], in, r0,     offL, c0, offR);
    issue_row(buf[3], in, r0 + 1, offL, c0, offR);

    #pragma unroll
    for (int i = 0; i < 20; ++i) {
        // Issue row i+4 first: 15 loads outstanding, then wait back to 12.
        if (i + 4 < 20)
            issue_row(buf[(i + 4) % 5], in, r0 + 2 + i, offL, c0, offR);

        if      (i <= 15) WAITVM(12);   // rows i+1..i+4 stay in flight
        else if (i == 16) WAITVM(9);
        else if (i == 17) WAITVM(6);
        else if (i == 18) WAITVM(3);
        else              WAITVM(0);

        const int   rr   = r0 - 2 + i;
        const float mrow = ((unsigned)rr < (unsigned)H) ? 1.f : 0.f;
        const int   s    = i % 5;       // static after full unroll
        hsum4(buf[s], mrow, mL, mR, h[0][s], h[1][s], h[2][s], h[3][s]);

        if (i >= 4) {
            float4 o;
            o.x = (h[0][0] + h[0][1] + h[0][2] + h[0][3] + h[0][4]) * scale;
            o.y = (h[1][0] + h[1][1] + h[1][2] + h[1][3] + h[1][4]) * scale;
            o.z = (h[2][0] + h[2][1] + h[2][2] + h[2][3] + h[2][4]) * scale;
            o.w = (h[3][0] + h[3][1] + h[3][2] + h[3][3] + h[3][4]) * scale;
            *reinterpret_cast<float4*>(op + (size_t)(i - 4) * W) = o;
        }
    }
}

extern "C" void kernel_launch(void* const* d_in, const int* in_sizes, int n_in,
                              void* d_out, int out_size, void* d_ws, size_t ws_size,
                              hipStream_t stream) {
    const float* x   = (const float*)d_in[0];
    const float* wgt = (const float*)d_in[1];
    float* out = (float*)d_out;

    dim3 grid(H / RB, 16 * 8);   // 16 bands x 128 planes = 2048 blocks
    dim3 block(256);
    avefilter_kernel<<<grid, block, 0, stream>>>(x, wgt, out);
}